// Round 2
// baseline (183.698 us; speedup 1.0000x reference)
//
#include <hip/hip_runtime.h>
#include <hip/hip_bf16.h>
#include <stdint.h>

// Conv2d: x[128][256][256] (f32), w[256][128][3][3] (f32), bias[256] (f32)
// out[256][256][256] (f32).  pad=1, stride=1.
// Strategy: bf16 MFMA implicit GEMM. M=COUT=256, N=65536 pixels, K=128ch x 9 taps.
//   ws layout: x_p bf16 [258][258][128] (padded, channel-innermost) = 17,040,384 B
//              W_pk bf16 [9][256][128]                              =    589,824 B
// R2 change: staging via plain global_load_dwordx4 + ds_write_b128 (no
// global_load_lds — its masked-EXEC / divergent-base semantics are the prime
// suspect for R1's absmax=2.7 structured corruption).

#define CIN   128
#define COUT  256
#define HH    256
#define WW    256
#define HP    258
#define WP    258
#define XP_ELEMS (HP * WP * CIN)   // 8,520,192 bf16 elements

typedef __attribute__((ext_vector_type(8))) __bf16 bf16x8;
typedef __attribute__((ext_vector_type(4))) float  floatx4;
typedef __attribute__((ext_vector_type(8))) short  short8;

// ---------------- prep 1: zero the padded border of x_p ----------------
__global__ void zero_border(unsigned short* __restrict__ xp) {
    int p  = blockIdx.x;          // 0..1027 border pixels
    int ch = threadIdx.x;         // 0..127
    int hp, wp;
    if (p < 258)      { hp = 0;   wp = p; }
    else if (p < 516) { hp = 257; wp = p - 258; }
    else { int s = p - 516; hp = 1 + (s >> 1); wp = (s & 1) * 257; }
    xp[(hp * WP + wp) * CIN + ch] = 0;
}

// ---------------- prep 2: transpose+cast x[c][h][w] -> x_p[h+1][w+1][c] ----------------
__global__ __launch_bounds__(256) void xpose_pad(const float* __restrict__ x,
                                                 unsigned short* __restrict__ xp) {
    __shared__ __align__(16) unsigned short tile[64][136];  // pad 128->136 (16B-aligned rows)
    int h  = blockIdx.x;            // 0..255
    int w0 = blockIdx.y << 6;       // 0,64,128,192
    int t  = threadIdx.x;
    int wl  = t & 63;               // 0..63
    int icq = t >> 6;               // 0..3
    const float* src = x + h * WW + w0 + wl;
#pragma unroll
    for (int icb = 0; icb < 32; ++icb) {
        int ic = icb * 4 + icq;
        __hip_bfloat16 b = __float2bfloat16(src[ic * (HH * WW)]);
        tile[wl][ic] = __builtin_bit_cast(unsigned short, b);
    }
    __syncthreads();
    int wl2 = t >> 2, q = t & 3;    // 64 rows x 4 chunks of 64B
    const short8* s8 = (const short8*)&tile[wl2][q * 32];
    short8* d8 = (short8*)(xp + ((size_t)(h + 1) * WP + (w0 + 1) + wl2) * CIN + q * 32);
#pragma unroll
    for (int i = 0; i < 4; ++i) d8[i] = s8[i];
}

// ---------------- prep 3: pack weights -> bf16 W_pk[kk][o][ic] ----------------
__global__ __launch_bounds__(256) void wpack(const float* __restrict__ w,
                                             unsigned short* __restrict__ wp) {
    int idx = blockIdx.x * 256 + threadIdx.x;   // 0..294911
    int kk  = idx >> 15;                        // / (256*128)
    int rem = idx & 32767;                      // o*128 + ic
    __hip_bfloat16 b = __float2bfloat16(w[rem * 9 + kk]);
    wp[idx] = __builtin_bit_cast(unsigned short, b);
}

// ---------------- main: 128x128 output tile, 4 waves, 16x16x32 bf16 MFMA ----------------
// LDS: flat chunks of 16B; chunk id = p*130 + c, p = (r(kh)*4 + icg), c = col 0..129.
// B-frag for (kh,lg) at col n reads chunk ((kh*4+lg)*130 + n) — 16 consecutive
// chunks per 16-lane group => uniform bank use (2-way, free).
__global__ __launch_bounds__(256, 3) void conv_mfma(
    const unsigned short* __restrict__ xp,   // [258][258][128] bf16
    const unsigned short* __restrict__ wpk,  // [9][256][128]   bf16
    const float* __restrict__ bias,          // [256] f32
    float* __restrict__ out) {               // [256][65536] f32
    __shared__ __align__(16) unsigned short x_lds[12 * 130 * 8];   // 24,960 B

    const int tid  = threadIdx.x;
    const int lane = tid & 63;
    const int wv   = tid >> 6;          // 0..3
    const int l15  = lane & 15;
    const int lg   = lane >> 4;         // 0..3
    const int h  = blockIdx.x >> 1;
    const int w0 = (blockIdx.x & 1) << 7;
    const int m0 = blockIdx.y << 7;
    const int wave_m = (wv >> 1) << 6;  // 0 or 64
    const int wave_n = (wv & 1) << 6;   // 0 or 64

    floatx4 acc[4][4];
#pragma unroll
    for (int fi = 0; fi < 4; ++fi)
#pragma unroll
        for (int fj = 0; fj < 4; ++fj) {
            floatx4 z = {0.f, 0.f, 0.f, 0.f};
            acc[fi][fj] = z;
        }

    for (int ic0 = 0; ic0 < CIN; ic0 += 32) {
        __syncthreads();   // protect LDS reuse (reads of prev iter done)
        // stage 12 planes x 130 cols = 1560 16B-chunks with 256 threads
#pragma unroll
        for (int it = 0; it < 7; ++it) {
            int id = it * 256 + tid;
            if (it < 6 || id < 1560) {
                int p = id / 130;           // plane: r = p>>2, icg = p&3
                int c = id - p * 130;       // col within plane
                int r = p >> 2, icg = p & 3;
                const uint4* g = (const uint4*)(
                    xp + ((size_t)(h + r) * WP + w0 + c) * CIN + ic0 + icg * 8);
                *(uint4*)(x_lds + (size_t)id * 8) = *g;
            }
        }
        __syncthreads();   // ds_writes visible to all waves

        const unsigned short* wbase =
            wpk + (size_t)(m0 + wave_m + l15) * CIN + ic0 + lg * 8;
#pragma unroll
        for (int kh = 0; kh < 3; ++kh) {
#pragma unroll
            for (int kw = 0; kw < 3; ++kw) {
                const int kk = kh * 3 + kw;
                bf16x8 a[4], b[4];
#pragma unroll
                for (int fi = 0; fi < 4; ++fi)
                    a[fi] = *(const bf16x8*)(wbase + kk * (COUT * CIN) + fi * 16 * CIN);
#pragma unroll
                for (int fj = 0; fj < 4; ++fj)
                    b[fj] = *(const bf16x8*)(
                        x_lds + ((kh * 4 + lg) * 130 + (wave_n + fj * 16 + l15 + kw)) * 8);
#pragma unroll
                for (int fi = 0; fi < 4; ++fi)
#pragma unroll
                    for (int fj = 0; fj < 4; ++fj)
                        acc[fi][fj] = __builtin_amdgcn_mfma_f32_16x16x32_bf16(
                            a[fi], b[fj], acc[fi][fj], 0, 0, 0);
            }
        }
    }

    // epilogue: D row=(lane>>4)*4+reg, col=lane&15 ; add bias, store f32
    const int nbase = h * WW + w0 + wave_n + l15;
#pragma unroll
    for (int fi = 0; fi < 4; ++fi) {
        int mrow = m0 + wave_m + fi * 16 + lg * 4;
#pragma unroll
        for (int r = 0; r < 4; ++r) {
            float bv = bias[mrow + r];
#pragma unroll
            for (int fj = 0; fj < 4; ++fj)
                out[(size_t)(mrow + r) * (HH * WW) + nbase + fj * 16] = acc[fi][fj][r] + bv;
        }
    }
}

extern "C" void kernel_launch(void* const* d_in, const int* in_sizes, int n_in,
                              void* d_out, int out_size, void* d_ws, size_t ws_size,
                              hipStream_t stream) {
    (void)in_sizes; (void)n_in; (void)out_size; (void)ws_size;
    const float* x    = (const float*)d_in[0];   // 128*256*256
    const float* w    = (const float*)d_in[1];   // 256*128*3*3
    const float* bias = (const float*)d_in[2];   // 256
    float* out = (float*)d_out;

    unsigned short* xp  = (unsigned short*)d_ws;            // bf16 [258][258][128]
    unsigned short* wpk = xp + XP_ELEMS;                    // bf16 [9][256][128]

    zero_border<<<dim3(1028), dim3(128), 0, stream>>>(xp);
    xpose_pad<<<dim3(256, 4), dim3(256), 0, stream>>>(x, xp);
    wpack<<<dim3(1152), dim3(256), 0, stream>>>(w, wpk);
    conv_mfma<<<dim3(512, 2), dim3(256), 0, stream>>>(xp, wpk, bias, out);
}